// Round 9
// baseline (807.171 us; speedup 1.0000x reference)
//
#include <hip/hip_runtime.h>

#define N_NODES 100000
#define N_EDGES 1200000
#define BK 128                    // nodes per bucket
#define NB 782                    // ceil(100000/128)
#define CHUNK_E 8192
#define NBLK_E 147                // ceil(N_EDGES / CHUNK_E)
#define TOT_H (NB * NBLK_E)       // 114954
#define NSB2 ((TOT_H + 1023) / 1024)   // 113

// Workspace layout (bytes), total ~44.1 MB:
//   hist_g  : [0, 460032)              NB*NBLK_E int, bucket-major
//   hs_scan : [460032, 920064)         exclusive scan of hist_g (block-local)
//   blk2    : [920064, 920576)         113 int scan block sums
//   pairs   : [920576, 5720576)        1200000 uint packed (src<<7)|(dst&127)
//   y1/y2   : [5720576, 18520576)      y1: bf16[100000*64]; reused as y2: f32[100000*16]
//   h1      : [18520576, 44120576)     f32[100000*64]; z1 then relu(z1+mean) in place
#define OFF_HISTG  0
#define OFF_HSCAN  460032
#define OFF_BLK2   920064
#define OFF_PAIRS  920576
#define OFF_Y1     5720576
#define OFF_H1     18520576

__device__ __forceinline__ unsigned short f2bf(float f) {
    unsigned u = __float_as_uint(f);
    unsigned r = (u + 0x7fffu + ((u >> 16) & 1u)) >> 16;   // RNE
    return (unsigned short)r;
}

// ---- CSR-lite build: bucket-grouped edge pairs (no per-node sort needed) ----

__global__ __launch_bounds__(512) void chunk_hist_kernel(
    const int* __restrict__ dst, int* __restrict__ hist_g)
{
    __shared__ int h[NB];
    const int e0 = blockIdx.x * CHUNK_E;
    const int e1 = min(e0 + CHUNK_E, N_EDGES);
    for (int i = threadIdx.x; i < NB; i += 512) h[i] = 0;
    __syncthreads();
    for (int e = e0 + threadIdx.x; e < e1; e += 512)
        atomicAdd(&h[dst[e] >> 7], 1);
    __syncthreads();
    for (int i = threadIdx.x; i < NB; i += 512)
        hist_g[i * NBLK_E + blockIdx.x] = h[i];
}

__global__ __launch_bounds__(1024) void scan2_blocks_kernel(
    const int* __restrict__ hist_g, int* __restrict__ hs_scan, int* __restrict__ blk2)
{
    __shared__ int s[1024];
    int i = blockIdx.x * 1024 + threadIdx.x;
    int v = (i < TOT_H) ? hist_g[i] : 0;
    s[threadIdx.x] = v;
    __syncthreads();
    for (int off = 1; off < 1024; off <<= 1) {
        int t = (threadIdx.x >= off) ? s[threadIdx.x - off] : 0;
        __syncthreads();
        s[threadIdx.x] += t;
        __syncthreads();
    }
    if (i < TOT_H) hs_scan[i] = s[threadIdx.x] - v;
    if (threadIdx.x == 1023) blk2[blockIdx.x] = s[1023];
}

__global__ __launch_bounds__(128) void scan2_tops_kernel(int* __restrict__ blk2)
{
    __shared__ int s[128];
    int v = (threadIdx.x < NSB2) ? blk2[threadIdx.x] : 0;
    s[threadIdx.x] = v;
    __syncthreads();
    for (int off = 1; off < 128; off <<= 1) {
        int t = (threadIdx.x >= off) ? s[threadIdx.x - off] : 0;
        __syncthreads();
        s[threadIdx.x] += t;
        __syncthreads();
    }
    if (threadIdx.x < NSB2) blk2[threadIdx.x] = s[threadIdx.x] - v;  // exclusive
}

__global__ __launch_bounds__(512) void pair_scatter_kernel(
    const int* __restrict__ src, const int* __restrict__ dst,
    const int* __restrict__ hs_scan, const int* __restrict__ blk2,
    unsigned* __restrict__ pairs)
{
    __shared__ int base_s[NB];
    __shared__ int cur_s[NB];
    const int b = blockIdx.x;
    const int e0 = b * CHUNK_E;
    const int e1 = min(e0 + CHUNK_E, N_EDGES);

    for (int i = threadIdx.x; i < NB; i += 512) {
        int idx = i * NBLK_E + b;
        base_s[i] = hs_scan[idx] + blk2[idx >> 10];
        cur_s[i] = 0;
    }
    __syncthreads();
    for (int e = e0 + threadIdx.x; e < e1; e += 512) {
        int d = dst[e];
        int bk = d >> 7;
        int pos = base_s[bk] + atomicAdd(&cur_s[bk], 1);
        pairs[pos] = ((unsigned)src[e] << 7) | (unsigned)(d & 127);
    }
}

// ---- Dense transforms (weights-in-lanes, nodes streamed through LDS) ----

__global__ __launch_bounds__(256) void dense1_kernel(
    const float* __restrict__ x,
    const float* __restrict__ Wn, const float* __restrict__ Ws,
    const float* __restrict__ b,
    unsigned short* __restrict__ y1, float* __restrict__ z1)
{
    __shared__ float sx[32 * 64];
    const int t = threadIdx.x;
    const int w = t >> 6;
    const int lane = t & 63;
    const int half = w >> 1;
    const int nsub = (w & 1) * 16;
    const int chunk = blockIdx.x * 32;

    {
        const float4* gx = (const float4*)(x + (size_t)chunk * 64);
        float4* sx4 = (float4*)sx;
        sx4[t] = gx[t];
        sx4[t + 256] = gx[t + 256];
    }

    const float* W = half ? Ws : Wn;
    float wr[64];
#pragma unroll
    for (int k = 0; k < 64; ++k) wr[k] = W[k * 64 + lane];
    const float bj = half ? b[lane] : 0.f;

    __syncthreads();

#pragma unroll 1
    for (int m = 0; m < 16; ++m) {
        const int node = nsub + m;
        const float4* xr = (const float4*)(sx + node * 64);
        float a0 = 0.f, a1 = 0.f, a2 = 0.f, a3 = 0.f;
#pragma unroll
        for (int k4 = 0; k4 < 16; ++k4) {
            float4 v = xr[k4];            // broadcast ds_read_b128
            a0 += v.x * wr[4 * k4 + 0];
            a1 += v.y * wr[4 * k4 + 1];
            a2 += v.z * wr[4 * k4 + 2];
            a3 += v.w * wr[4 * k4 + 3];
        }
        const float o = (a0 + a1) + (a2 + a3) + bj;
        const size_t gn = (size_t)(chunk + node);
        if (half) z1[gn * 64 + lane] = o;
        else      y1[gn * 64 + lane] = f2bf(o);
    }
}

__global__ __launch_bounds__(256) void dense2_kernel(
    const float* __restrict__ h1,
    const float* __restrict__ Wn, const float* __restrict__ Ws,
    const float* __restrict__ b,
    float* __restrict__ y2, float* __restrict__ out)
{
    __shared__ float sx[32 * 68];
    const int t = threadIdx.x;
    const int w = t >> 6;
    const int lane = t & 63;
    const int half = w >> 1;
    const int nsub = (w & 1) * 16;
    const int j = lane & 15;
    const int g = lane >> 4;
    const int chunk = blockIdx.x * 32;

    {
        const float4* gx = (const float4*)(h1 + (size_t)chunk * 64);
        float4* sx4 = (float4*)sx;
        int r0 = t >> 4, c0 = t & 15;
        sx4[r0 * 17 + c0] = gx[t];
        sx4[(r0 + 16) * 17 + c0] = gx[t + 256];
    }

    const float* W = half ? Ws : Wn;
    float wr[64];
#pragma unroll
    for (int k = 0; k < 64; ++k) wr[k] = W[k * 16 + j];
    const float bj = half ? b[j] : 0.f;

    __syncthreads();

#pragma unroll 1
    for (int q = 0; q < 4; ++q) {
        const int node = nsub + q * 4 + g;
        const float4* xr = (const float4*)(sx + node * 68);
        float a0 = 0.f, a1 = 0.f, a2 = 0.f, a3 = 0.f;
#pragma unroll
        for (int k4 = 0; k4 < 16; ++k4) {
            float4 v = xr[k4];
            a0 += v.x * wr[4 * k4 + 0];
            a1 += v.y * wr[4 * k4 + 1];
            a2 += v.z * wr[4 * k4 + 2];
            a3 += v.w * wr[4 * k4 + 3];
        }
        const float o = (a0 + a1) + (a2 + a3) + bj;
        const size_t gn = (size_t)(chunk + node);
        if (half) out[gn * 16 + j] = o;
        else      y2[gn * 16 + j] = o;
    }
}

// ---- Fused bucket aggregation (replaces within-bucket sort + wave gather) ----
// One block per 128-node bucket. Gather y[src] rows for the bucket's contiguous
// edge run and LDS-atomicAdd into per-node accumulators; degree counted inline;
// epilogue writes relu(z + acc/deg) coalesced. Pad 65 -> bank (node+8fl+j)%32.

__global__ __launch_bounds__(512) void agg1_kernel(
    const unsigned short* __restrict__ y1,
    const unsigned* __restrict__ pairs,
    const int* __restrict__ hs_scan, const int* __restrict__ blk2,
    float* __restrict__ h1)
{
    __shared__ float acc[BK * 65];
    __shared__ int deg[BK];
    const int b = blockIdx.x;
    const int t = threadIdx.x;
    const int lane = t & 63;
    const int wv = t >> 6;          // 8 waves
    const int g = lane >> 3;        // 8 edge slots
    const int fl = lane & 7;        // uint4 chunk: features fl*8..fl*8+7

    for (int i = t; i < BK * 65; i += 512) acc[i] = 0.f;
    for (int i = t; i < BK; i += 512) deg[i] = 0;

    const int i0 = b * NBLK_E;
    const int start = hs_scan[i0] + blk2[i0 >> 10];
    const int end = (b == NB - 1) ? N_EDGES
                    : hs_scan[i0 + NBLK_E] + blk2[(i0 + NBLK_E) >> 10];
    __syncthreads();

    for (int base = start + wv * 64; base < end; base += 512) {
        const int m = min(64, end - base);
        unsigned eid = 0;
        if (lane < m) eid = pairs[base + lane];
        for (int jj = 0; jj < m; jj += 8) {
            const int idx = jj + g;
            const unsigned u = __shfl(eid, idx);
            if (idx < m) {
                const int s = (int)(u >> 7);
                const int dl = (int)(u & 127u);
                uint4 raw = ((const uint4*)(y1 + (size_t)s * 64))[fl];
                float* a = acc + dl * 65 + fl * 8;
                atomicAdd(a + 0, __uint_as_float(raw.x << 16));
                atomicAdd(a + 1, __uint_as_float(raw.x & 0xffff0000u));
                atomicAdd(a + 2, __uint_as_float(raw.y << 16));
                atomicAdd(a + 3, __uint_as_float(raw.y & 0xffff0000u));
                atomicAdd(a + 4, __uint_as_float(raw.z << 16));
                atomicAdd(a + 5, __uint_as_float(raw.z & 0xffff0000u));
                atomicAdd(a + 6, __uint_as_float(raw.w << 16));
                atomicAdd(a + 7, __uint_as_float(raw.w & 0xffff0000u));
                if (fl == 0) atomicAdd(&deg[dl], 1);
            }
        }
    }
    __syncthreads();

    const int node0 = b * BK;
    for (int q = t; q < BK * 16; q += 512) {       // float4 chunks
        const int n = q >> 4;
        const int c = q & 15;
        const int gn = node0 + n;
        if (gn >= N_NODES) break;
        const float invd = 1.0f / (float)max(deg[n], 1);
        float4* hp = (float4*)(h1 + (size_t)gn * 64);
        float4 z = hp[c];
        const float* a = acc + n * 65 + c * 4;
        hp[c] = make_float4(fmaxf(z.x + a[0] * invd, 0.f),
                            fmaxf(z.y + a[1] * invd, 0.f),
                            fmaxf(z.z + a[2] * invd, 0.f),
                            fmaxf(z.w + a[3] * invd, 0.f));
    }
}

__global__ __launch_bounds__(512) void agg2_kernel(
    const float* __restrict__ y2,
    const unsigned* __restrict__ pairs,
    const int* __restrict__ hs_scan, const int* __restrict__ blk2,
    float* __restrict__ out)
{
    __shared__ float acc[BK * 17];
    __shared__ int deg[BK];
    const int b = blockIdx.x;
    const int t = threadIdx.x;
    const int lane = t & 63;
    const int wv = t >> 6;
    const int g = lane >> 2;        // 16 edge slots
    const int fl = lane & 3;        // float4 chunk of the 16-f32 row

    for (int i = t; i < BK * 17; i += 512) acc[i] = 0.f;
    for (int i = t; i < BK; i += 512) deg[i] = 0;

    const int i0 = b * NBLK_E;
    const int start = hs_scan[i0] + blk2[i0 >> 10];
    const int end = (b == NB - 1) ? N_EDGES
                    : hs_scan[i0 + NBLK_E] + blk2[(i0 + NBLK_E) >> 10];
    __syncthreads();

    for (int base = start + wv * 64; base < end; base += 512) {
        const int m = min(64, end - base);
        unsigned eid = 0;
        if (lane < m) eid = pairs[base + lane];
        for (int jj = 0; jj < m; jj += 16) {
            const int idx = jj + g;
            const unsigned u = __shfl(eid, idx);
            if (idx < m) {
                const int s = (int)(u >> 7);
                const int dl = (int)(u & 127u);
                float4 v = ((const float4*)(y2 + (size_t)s * 16))[fl];
                float* a = acc + dl * 17 + fl * 4;
                atomicAdd(a + 0, v.x);
                atomicAdd(a + 1, v.y);
                atomicAdd(a + 2, v.z);
                atomicAdd(a + 3, v.w);
                if (fl == 0) atomicAdd(&deg[dl], 1);
            }
        }
    }
    __syncthreads();

    const int node0 = b * BK;
    for (int q = t; q < BK * 4; q += 512) {        // float4 chunks of 16-f rows
        const int n = q >> 2;
        const int c = q & 3;
        const int gn = node0 + n;
        if (gn >= N_NODES) break;
        const float invd = 1.0f / (float)max(deg[n], 1);
        float4* op = (float4*)(out + (size_t)gn * 16);
        float4 z = op[c];
        const float* a = acc + n * 17 + c * 4;
        op[c] = make_float4(z.x + a[0] * invd, z.y + a[1] * invd,
                            z.z + a[2] * invd, z.w + a[3] * invd);
    }
}

extern "C" void kernel_launch(void* const* d_in, const int* in_sizes, int n_in,
                              void* d_out, int out_size, void* d_ws, size_t ws_size,
                              hipStream_t stream) {
    const float* x   = (const float*)d_in[0];
    const int*   src = (const int*)d_in[1];
    const int*   dst = (const int*)d_in[2];
    const float* W1s = (const float*)d_in[3];
    const float* W1n = (const float*)d_in[4];
    const float* b1  = (const float*)d_in[5];
    const float* W2s = (const float*)d_in[6];
    const float* W2n = (const float*)d_in[7];
    const float* b2  = (const float*)d_in[8];
    float* out = (float*)d_out;

    char* ws = (char*)d_ws;
    int* hist_g     = (int*)(ws + OFF_HISTG);
    int* hs_scan    = (int*)(ws + OFF_HSCAN);
    int* blk2       = (int*)(ws + OFF_BLK2);
    unsigned* pairs = (unsigned*)(ws + OFF_PAIRS);
    unsigned short* y1 = (unsigned short*)(ws + OFF_Y1);
    float* y2       = (float*)(ws + OFF_Y1);   // reuses y1 space after agg1
    float* h1       = (float*)(ws + OFF_H1);

    // bucket-grouped pairs (zero global atomics, no per-node sort)
    chunk_hist_kernel<<<NBLK_E, 512, 0, stream>>>(dst, hist_g);
    scan2_blocks_kernel<<<NSB2, 1024, 0, stream>>>(hist_g, hs_scan, blk2);
    scan2_tops_kernel<<<1, 128, 0, stream>>>(blk2);
    pair_scatter_kernel<<<NBLK_E, 512, 0, stream>>>(src, dst, hs_scan, blk2, pairs);

    // Layer 1
    dense1_kernel<<<3125, 256, 0, stream>>>(x, W1n, W1s, b1, y1, h1);
    agg1_kernel<<<NB, 512, 0, stream>>>(y1, pairs, hs_scan, blk2, h1);

    // Layer 2
    dense2_kernel<<<3125, 256, 0, stream>>>(h1, W2n, W2s, b2, y2, out);
    agg2_kernel<<<NB, 512, 0, stream>>>(y2, pairs, hs_scan, blk2, out);
}

// Round 10
// 245.777 us; speedup vs baseline: 3.2842x; 3.2842x over previous
//
#include <hip/hip_runtime.h>

#define N_NODES 100000
#define N_EDGES 1200000
#define NB 391                    // buckets of 256 dst nodes
#define CHUNK_E 4096
#define NBLK_E 293                // ceil(N_EDGES / CHUNK_E)
#define TOT_H (NB * NBLK_E)       // 114563
#define NSB2 ((TOT_H + 1023) / 1024)   // 112

// Workspace layout (bytes), total ~49.3 MB (round-8 layout):
#define OFF_ROWPTR 0
#define OFF_HISTG  400896
#define OFF_HSCAN  859648
#define OFF_BLK2   1318400
#define OFF_PAIRS  1318912
#define OFF_SORTED 6118912
#define OFF_Y1     10918912
#define OFF_H1     23718912

__device__ __forceinline__ unsigned short f2bf(float f) {
    unsigned u = __float_as_uint(f);
    unsigned r = (u + 0x7fffu + ((u >> 16) & 1u)) >> 16;   // RNE
    return (unsigned short)r;
}

// ---- CSR build (atomic-free radix pass over 256-node buckets) ----

__global__ __launch_bounds__(256) void chunk_hist_kernel(
    const int* __restrict__ dst, int* __restrict__ hist_g)
{
    __shared__ int h[NB];
    const int e0 = blockIdx.x * CHUNK_E;
    const int e1 = min(e0 + CHUNK_E, N_EDGES);
    for (int i = threadIdx.x; i < NB; i += 256) h[i] = 0;
    __syncthreads();
    for (int e = e0 + threadIdx.x; e < e1; e += 256)
        atomicAdd(&h[dst[e] >> 8], 1);
    __syncthreads();
    for (int i = threadIdx.x; i < NB; i += 256)
        hist_g[i * NBLK_E + blockIdx.x] = h[i];
}

__global__ __launch_bounds__(1024) void scan2_blocks_kernel(
    const int* __restrict__ hist_g, int* __restrict__ hs_scan, int* __restrict__ blk2)
{
    __shared__ int s[1024];
    int i = blockIdx.x * 1024 + threadIdx.x;
    int v = (i < TOT_H) ? hist_g[i] : 0;
    s[threadIdx.x] = v;
    __syncthreads();
    for (int off = 1; off < 1024; off <<= 1) {
        int t = (threadIdx.x >= off) ? s[threadIdx.x - off] : 0;
        __syncthreads();
        s[threadIdx.x] += t;
        __syncthreads();
    }
    if (i < TOT_H) hs_scan[i] = s[threadIdx.x] - v;
    if (threadIdx.x == 1023) blk2[blockIdx.x] = s[1023];
}

__global__ __launch_bounds__(128) void scan2_tops_kernel(int* __restrict__ blk2)
{
    __shared__ int s[128];
    int v = (threadIdx.x < NSB2) ? blk2[threadIdx.x] : 0;
    s[threadIdx.x] = v;
    __syncthreads();
    for (int off = 1; off < 128; off <<= 1) {
        int t = (threadIdx.x >= off) ? s[threadIdx.x - off] : 0;
        __syncthreads();
        s[threadIdx.x] += t;
        __syncthreads();
    }
    if (threadIdx.x < NSB2) blk2[threadIdx.x] = s[threadIdx.x] - v;  // exclusive
}

__global__ __launch_bounds__(256) void pair_scatter_kernel(
    const int* __restrict__ src, const int* __restrict__ dst,
    const int* __restrict__ hs_scan, const int* __restrict__ blk2,
    unsigned* __restrict__ pairs)
{
    __shared__ int base_s[NB];
    __shared__ int cur_s[NB];
    const int b = blockIdx.x;
    const int e0 = b * CHUNK_E;
    const int e1 = min(e0 + CHUNK_E, N_EDGES);

    for (int i = threadIdx.x; i < NB; i += 256) {
        int idx = i * NBLK_E + b;
        base_s[i] = hs_scan[idx] + blk2[idx >> 10];
        cur_s[i] = 0;
    }
    __syncthreads();
    for (int e = e0 + threadIdx.x; e < e1; e += 256) {
        int d = dst[e];
        int bk = d >> 8;
        int pos = base_s[bk] + atomicAdd(&cur_s[bk], 1);
        pairs[pos] = ((unsigned)src[e] << 8) | (unsigned)(d & 255);
    }
}

__global__ __launch_bounds__(256) void bucket_fill_plus_kernel(
    const unsigned* __restrict__ pairs,
    const int* __restrict__ hs_scan, const int* __restrict__ blk2,
    int* __restrict__ row_ptr, int* __restrict__ sorted_src)
{
    __shared__ int hist[256];
    __shared__ int sc[256];
    __shared__ int cur[256];
    const int b = blockIdx.x;
    const int t = threadIdx.x;

    int i0 = b * NBLK_E;
    const int start = hs_scan[i0] + blk2[i0 >> 10];
    int end;
    if (b == NB - 1) end = N_EDGES;
    else {
        int i1 = (b + 1) * NBLK_E;
        end = hs_scan[i1] + blk2[i1 >> 10];
    }

    hist[t] = 0;
    __syncthreads();
    for (int e = start + t; e < end; e += 256)
        atomicAdd(&hist[pairs[e] & 255u], 1);
    __syncthreads();

    int v = hist[t];
    sc[t] = v;
    __syncthreads();
    for (int off = 1; off < 256; off <<= 1) {
        int tv = (t >= off) ? sc[t - off] : 0;
        __syncthreads();
        sc[t] += tv;
        __syncthreads();
    }
    const int excl = sc[t] - v;
    const int node = (b << 8) + t;
    if (node < N_NODES) row_ptr[node] = start + excl;
    if (b == NB - 1 && t == 0) row_ptr[N_NODES] = N_EDGES;
    cur[t] = start + excl;
    __syncthreads();

    for (int e = start + t; e < end; e += 256) {
        unsigned u = pairs[e];
        int pos = atomicAdd(&cur[u & 255u], 1);
        sorted_src[pos] = (int)(u >> 8);
    }
}

// ---- Dense transforms (weights-in-lanes, nodes streamed through LDS) ----

__global__ __launch_bounds__(256) void dense1_kernel(
    const float* __restrict__ x,
    const float* __restrict__ Wn, const float* __restrict__ Ws,
    const float* __restrict__ b,
    unsigned short* __restrict__ y1, float* __restrict__ z1)
{
    __shared__ float sx[32 * 64];
    const int t = threadIdx.x;
    const int w = t >> 6;
    const int lane = t & 63;
    const int half = w >> 1;
    const int nsub = (w & 1) * 16;
    const int chunk = blockIdx.x * 32;

    {
        const float4* gx = (const float4*)(x + (size_t)chunk * 64);
        float4* sx4 = (float4*)sx;
        sx4[t] = gx[t];
        sx4[t + 256] = gx[t + 256];
    }

    const float* W = half ? Ws : Wn;
    float wr[64];
#pragma unroll
    for (int k = 0; k < 64; ++k) wr[k] = W[k * 64 + lane];
    const float bj = half ? b[lane] : 0.f;

    __syncthreads();

#pragma unroll 1
    for (int m = 0; m < 16; ++m) {
        const int node = nsub + m;
        const float4* xr = (const float4*)(sx + node * 64);
        float a0 = 0.f, a1 = 0.f, a2 = 0.f, a3 = 0.f;
#pragma unroll
        for (int k4 = 0; k4 < 16; ++k4) {
            float4 v = xr[k4];            // broadcast ds_read_b128
            a0 += v.x * wr[4 * k4 + 0];
            a1 += v.y * wr[4 * k4 + 1];
            a2 += v.z * wr[4 * k4 + 2];
            a3 += v.w * wr[4 * k4 + 3];
        }
        const float o = (a0 + a1) + (a2 + a3) + bj;
        const size_t gn = (size_t)(chunk + node);
        if (half) z1[gn * 64 + lane] = o;
        else      y1[gn * 64 + lane] = f2bf(o);
    }
}

__global__ __launch_bounds__(256) void dense2_kernel(
    const float* __restrict__ h1,
    const float* __restrict__ Wn, const float* __restrict__ Ws,
    const float* __restrict__ b,
    float* __restrict__ y2, float* __restrict__ out)
{
    __shared__ float sx[32 * 68];
    const int t = threadIdx.x;
    const int w = t >> 6;
    const int lane = t & 63;
    const int half = w >> 1;
    const int nsub = (w & 1) * 16;
    const int j = lane & 15;
    const int g = lane >> 4;
    const int chunk = blockIdx.x * 32;

    {
        const float4* gx = (const float4*)(h1 + (size_t)chunk * 64);
        float4* sx4 = (float4*)sx;
        int r0 = t >> 4, c0 = t & 15;
        sx4[r0 * 17 + c0] = gx[t];
        sx4[(r0 + 16) * 17 + c0] = gx[t + 256];
    }

    const float* W = half ? Ws : Wn;
    float wr[64];
#pragma unroll
    for (int k = 0; k < 64; ++k) wr[k] = W[k * 16 + j];
    const float bj = half ? b[j] : 0.f;

    __syncthreads();

#pragma unroll 1
    for (int q = 0; q < 4; ++q) {
        const int node = nsub + q * 4 + g;
        const float4* xr = (const float4*)(sx + node * 68);
        float a0 = 0.f, a1 = 0.f, a2 = 0.f, a3 = 0.f;
#pragma unroll
        for (int k4 = 0; k4 < 16; ++k4) {
            float4 v = xr[k4];
            a0 += v.x * wr[4 * k4 + 0];
            a1 += v.y * wr[4 * k4 + 1];
            a2 += v.z * wr[4 * k4 + 2];
            a3 += v.w * wr[4 * k4 + 3];
        }
        const float o = (a0 + a1) + (a2 + a3) + bj;
        const size_t gn = (size_t)(chunk + node);
        if (half) out[gn * 16 + j] = o;
        else      y2[gn * 16 + j] = o;
    }
}

// ---- Pure gathers ----

// h1[n] = relu(h1[n] + mean(y1[src])); 8 edges in flight, uint4 (16 B) per lane.
__global__ __launch_bounds__(256) void gather1_kernel(
    const unsigned short* __restrict__ y1,
    const int* __restrict__ row_ptr,
    const int* __restrict__ sorted_src,
    float* __restrict__ h1)
{
    const int w = threadIdx.x >> 6;
    const int lane = threadIdx.x & 63;
    const int n = blockIdx.x * 4 + w;
    const int g = lane >> 3;          // 8 edge slots
    const int fl = lane & 7;          // uint4 chunk: features fl*8..fl*8+7

    const int start = row_ptr[n];
    const int deg = row_ptr[n + 1] - start;

    float a0 = 0.f, a1 = 0.f, a2 = 0.f, a3 = 0.f;
    float a4 = 0.f, a5 = 0.f, a6 = 0.f, a7 = 0.f;
    for (int base = 0; base < deg; base += 64) {
        const int m = min(64, deg - base);
        int eid = 0;
        if (lane < m) eid = sorted_src[start + base + lane];
        for (int jj = 0; jj < m; jj += 8) {
            const int idx = jj + g;
            const int s = __shfl(eid, idx);
            if (idx < m) {
                uint4 raw = ((const uint4*)(y1 + (size_t)s * 64))[fl];
                a0 += __uint_as_float(raw.x << 16);
                a1 += __uint_as_float(raw.x & 0xffff0000u);
                a2 += __uint_as_float(raw.y << 16);
                a3 += __uint_as_float(raw.y & 0xffff0000u);
                a4 += __uint_as_float(raw.z << 16);
                a5 += __uint_as_float(raw.z & 0xffff0000u);
                a6 += __uint_as_float(raw.w << 16);
                a7 += __uint_as_float(raw.w & 0xffff0000u);
            }
        }
    }
#pragma unroll
    for (int d = 8; d <= 32; d <<= 1) {
        a0 += __shfl_xor(a0, d); a1 += __shfl_xor(a1, d);
        a2 += __shfl_xor(a2, d); a3 += __shfl_xor(a3, d);
        a4 += __shfl_xor(a4, d); a5 += __shfl_xor(a5, d);
        a6 += __shfl_xor(a6, d); a7 += __shfl_xor(a7, d);
    }

    const float invd = 1.0f / (float)max(deg, 1);
    if (g == 0) {
        float4* hp = (float4*)(h1 + (size_t)n * 64);
        float4 z0 = hp[fl * 2];
        float4 z1v = hp[fl * 2 + 1];
        hp[fl * 2] = make_float4(fmaxf(z0.x + a0 * invd, 0.f),
                                 fmaxf(z0.y + a1 * invd, 0.f),
                                 fmaxf(z0.z + a2 * invd, 0.f),
                                 fmaxf(z0.w + a3 * invd, 0.f));
        hp[fl * 2 + 1] = make_float4(fmaxf(z1v.x + a4 * invd, 0.f),
                                     fmaxf(z1v.y + a5 * invd, 0.f),
                                     fmaxf(z1v.z + a6 * invd, 0.f),
                                     fmaxf(z1v.w + a7 * invd, 0.f));
    }
}

// out[n] += mean(y2[src]); 16 edges in flight, float4 per lane.
__global__ __launch_bounds__(256) void gather2_kernel(
    const float* __restrict__ y2,
    const int* __restrict__ row_ptr,
    const int* __restrict__ sorted_src,
    float* __restrict__ out)
{
    const int w = threadIdx.x >> 6;
    const int lane = threadIdx.x & 63;
    const int n = blockIdx.x * 4 + w;
    const int group = lane >> 2;
    const int fl = lane & 3;

    const int start = row_ptr[n];
    const int deg = row_ptr[n + 1] - start;

    float4 acc = make_float4(0.f, 0.f, 0.f, 0.f);
    for (int base = 0; base < deg; base += 64) {
        const int m = min(64, deg - base);
        int eid = 0;
        if (lane < m) eid = sorted_src[start + base + lane];
        for (int jj = 0; jj < m; jj += 16) {
            const int idx = jj + group;
            const int s = __shfl(eid, idx);
            if (idx < m) {
                float4 v = ((const float4*)(y2 + (size_t)s * 16))[fl];
                acc.x += v.x; acc.y += v.y; acc.z += v.z; acc.w += v.w;
            }
        }
    }
#pragma unroll
    for (int d = 4; d <= 32; d <<= 1) {
        acc.x += __shfl_xor(acc.x, d); acc.y += __shfl_xor(acc.y, d);
        acc.z += __shfl_xor(acc.z, d); acc.w += __shfl_xor(acc.w, d);
    }
    const float invd = 1.0f / (float)max(deg, 1);
    if (lane < 4) {
        float4* op = (float4*)(out + (size_t)n * 16);
        float4 z = op[fl];
        op[fl] = make_float4(z.x + acc.x * invd, z.y + acc.y * invd,
                             z.z + acc.z * invd, z.w + acc.w * invd);
    }
}

extern "C" void kernel_launch(void* const* d_in, const int* in_sizes, int n_in,
                              void* d_out, int out_size, void* d_ws, size_t ws_size,
                              hipStream_t stream) {
    const float* x   = (const float*)d_in[0];
    const int*   src = (const int*)d_in[1];
    const int*   dst = (const int*)d_in[2];
    const float* W1s = (const float*)d_in[3];
    const float* W1n = (const float*)d_in[4];
    const float* b1  = (const float*)d_in[5];
    const float* W2s = (const float*)d_in[6];
    const float* W2n = (const float*)d_in[7];
    const float* b2  = (const float*)d_in[8];
    float* out = (float*)d_out;

    char* ws = (char*)d_ws;
    int* row_ptr    = (int*)(ws + OFF_ROWPTR);
    int* hist_g     = (int*)(ws + OFF_HISTG);
    int* hs_scan    = (int*)(ws + OFF_HSCAN);
    int* blk2       = (int*)(ws + OFF_BLK2);
    unsigned* pairs = (unsigned*)(ws + OFF_PAIRS);
    int* sorted_src = (int*)(ws + OFF_SORTED);
    unsigned short* y1 = (unsigned short*)(ws + OFF_Y1);
    float* y2       = (float*)(ws + OFF_Y1);   // reuses y1 space after gather1
    float* h1       = (float*)(ws + OFF_H1);

    // CSR build: radix pass, zero global atomics
    chunk_hist_kernel<<<NBLK_E, 256, 0, stream>>>(dst, hist_g);
    scan2_blocks_kernel<<<NSB2, 1024, 0, stream>>>(hist_g, hs_scan, blk2);
    scan2_tops_kernel<<<1, 128, 0, stream>>>(blk2);
    pair_scatter_kernel<<<NBLK_E, 256, 0, stream>>>(src, dst, hs_scan, blk2, pairs);
    bucket_fill_plus_kernel<<<NB, 256, 0, stream>>>(pairs, hs_scan, blk2, row_ptr, sorted_src);

    // Layer 1
    dense1_kernel<<<3125, 256, 0, stream>>>(x, W1n, W1s, b1, y1, h1);
    gather1_kernel<<<N_NODES / 4, 256, 0, stream>>>(y1, row_ptr, sorted_src, h1);

    // Layer 2
    dense2_kernel<<<3125, 256, 0, stream>>>(h1, W2n, W2s, b2, y2, out);
    gather2_kernel<<<N_NODES / 4, 256, 0, stream>>>(y2, row_ptr, sorted_src, out);
}